// Round 1
// baseline (375.869 us; speedup 1.0000x reference)
//
#include <hip/hip_runtime.h>
#include <hip/hip_bf16.h>

// ChebyshevKANLayer: y[b,o] = sum_{i,j} T_j(xhat[b,i]) * C[i,o,j]
//   == GEMM  M=8192 (batch), N=1024 (out), K=1024*9=9216, bf16 inputs, fp32 acc.
// ws layout: [0,64K) row stats | [64K, +18.9MB) B^T bf16 [O][K] | [+, +151MB) A bf16 [M][K]

typedef __attribute__((ext_vector_type(8))) short bf16x8s;   // 8 bf16 = 4 VGPRs (MFMA A/B frag)
typedef __attribute__((ext_vector_type(4))) float f32x4;     // MFMA C/D frag

constexpr int BROWS = 8192;
constexpr int IDIM  = 1024;
constexpr int ODIM  = 1024;
constexpr int DEG1  = 9;
constexpr int KDIM  = IDIM * DEG1;   // 9216

// ---------- 1. per-row min/max -> (scale, offset):  xhat = scale*x + offset ----------
__global__ __launch_bounds__(256) void rowstats_kernel(const float* __restrict__ x,
                                                       float* __restrict__ stats) {
  const int row  = blockIdx.x * 4 + (threadIdx.x >> 6);   // one wave per row
  const int lane = threadIdx.x & 63;
  const float4* xr = (const float4*)(x + (size_t)row * IDIM);
  float mn = 3.402823466e38f, mx = -3.402823466e38f;
#pragma unroll
  for (int c = 0; c < 4; ++c) {                            // 4*64 float4 = 1024 floats
    float4 v = xr[lane + c * 64];
    mn = fminf(mn, fminf(fminf(v.x, v.y), fminf(v.z, v.w)));
    mx = fmaxf(mx, fmaxf(fmaxf(v.x, v.y), fmaxf(v.z, v.w)));
  }
#pragma unroll
  for (int off = 32; off >= 1; off >>= 1) {
    mn = fminf(mn, __shfl_xor(mn, off));
    mx = fmaxf(mx, __shfl_xor(mx, off));
  }
  if (lane == 0) {
    float inv = 2.0f / (mx - mn);
    stats[row * 2 + 0] = inv;                 // scale
    stats[row * 2 + 1] = -mn * inv - 1.0f;    // offset
  }
}

// ---------- 2. A[b][i*9+j] = T_j(xhat[b,i]) as bf16 ----------
__global__ __launch_bounds__(256) void build_a_kernel(const float* __restrict__ x,
                                                      const float* __restrict__ stats,
                                                      __hip_bfloat16* __restrict__ A2) {
  const int gid = blockIdx.x * 256 + threadIdx.x;
  const int b = gid >> 10;
  const int i = gid & 1023;
  const float xv = x[(size_t)b * IDIM + i];
  const float sc = stats[b * 2 + 0];
  const float of = stats[b * 2 + 1];
  const float xn = fmaf(sc, xv, of);          // in [-1, 1]
  float T[DEG1];
  T[0] = 1.0f;
  T[1] = xn;
#pragma unroll
  for (int n = 2; n < DEG1; ++n) T[n] = 2.0f * xn * T[n - 1] - T[n - 2];
  __hip_bfloat16* dst = A2 + (size_t)b * KDIM + i * DEG1;  // 18 contiguous bytes/thread
#pragma unroll
  for (int j = 0; j < DEG1; ++j) dst[j] = __float2bfloat16(T[j]);
}

// ---------- 3. B^T[o][i*9+j] = C[i][o][j] as bf16 (k-contiguous rows) ----------
__global__ __launch_bounds__(256) void build_b_kernel(const float* __restrict__ coeffs,
                                                      __hip_bfloat16* __restrict__ B2T) {
  const int gid = blockIdx.x * 256 + threadIdx.x;
  const int o = gid >> 10;
  const int i = gid & 1023;      // lanes vary i -> coalesced 18B-chunk writes
  const float* cp = coeffs + ((size_t)i * ODIM + o) * DEG1;
  __hip_bfloat16* dst = B2T + (size_t)o * KDIM + i * DEG1;
#pragma unroll
  for (int j = 0; j < DEG1; ++j) dst[j] = __float2bfloat16(cp[j]);
}

// ---------- 4. GEMM: 128x128 tile, BK=32, 4 waves x (4x4) 16x16x32 bf16 MFMA ----------
__global__ __launch_bounds__(256) void gemm_kernel(const ushort* __restrict__ A2,
                                                   const ushort* __restrict__ B2T,
                                                   float* __restrict__ out) {
  constexpr int BK = 32;
  constexpr int ASTR = 40;   // 32 + 8 pad; row stride 80 B keeps 16-B alignment
  __shared__ __align__(16) ushort As[128 * ASTR];
  __shared__ __align__(16) ushort Bs[128 * ASTR];

  const int t    = threadIdx.x;
  const int wave = t >> 6;
  const int lane = t & 63;
  const int wr   = wave >> 1;          // wave row 0..1 (64 rows each)
  const int wc   = wave & 1;           // wave col 0..1 (64 cols each)
  const int c16  = lane & 15;
  const int quad = lane >> 4;
  const int rowBase = blockIdx.y * 128;
  const int colBase = blockIdx.x * 128;

  // staging: 256 threads * 2 vec8 each per operand = 128 rows * 32 k
  const int srow = t >> 2;             // 0..63
  const int skc  = (t & 3) * 8;        // 0,8,16,24
  const ushort* aptr0 = A2  + (size_t)(rowBase + srow) * KDIM + skc;
  const ushort* aptr1 = aptr0 + (size_t)64 * KDIM;
  const ushort* bptr0 = B2T + (size_t)(colBase + srow) * KDIM + skc;
  const ushort* bptr1 = bptr0 + (size_t)64 * KDIM;
  const int woff0 = srow * ASTR + skc;
  const int woff1 = woff0 + 64 * ASTR;

  f32x4 acc[4][4];
#pragma unroll
  for (int a = 0; a < 4; ++a)
#pragma unroll
    for (int b = 0; b < 4; ++b) acc[a][b] = (f32x4){0.f, 0.f, 0.f, 0.f};

  for (int k0 = 0; k0 < KDIM; k0 += BK) {
    const uint4 av0 = *(const uint4*)(aptr0 + k0);
    const uint4 av1 = *(const uint4*)(aptr1 + k0);
    const uint4 bv0 = *(const uint4*)(bptr0 + k0);
    const uint4 bv1 = *(const uint4*)(bptr1 + k0);
    __syncthreads();                       // previous tile fully consumed
    *(uint4*)&As[woff0] = av0;
    *(uint4*)&As[woff1] = av1;
    *(uint4*)&Bs[woff0] = bv0;
    *(uint4*)&Bs[woff1] = bv1;
    __syncthreads();                       // tile visible to all waves

    bf16x8s afr[4], bfr[4];
#pragma unroll
    for (int tm = 0; tm < 4; ++tm)         // A frag: m = lane&15, k = quad*8+j
      afr[tm] = *(const bf16x8s*)&As[(wr * 64 + tm * 16 + c16) * ASTR + quad * 8];
#pragma unroll
    for (int tn = 0; tn < 4; ++tn)         // B frag: n = lane&15, k = quad*8+j
      bfr[tn] = *(const bf16x8s*)&Bs[(wc * 64 + tn * 16 + c16) * ASTR + quad * 8];
#pragma unroll
    for (int tm = 0; tm < 4; ++tm)
#pragma unroll
      for (int tn = 0; tn < 4; ++tn)
        acc[tm][tn] = __builtin_amdgcn_mfma_f32_16x16x32_bf16(afr[tm], bfr[tn],
                                                              acc[tm][tn], 0, 0, 0);
  }

  // epilogue: C/D mapping col = lane&15, row = quad*4 + r  (verified m89/m91)
#pragma unroll
  for (int tm = 0; tm < 4; ++tm)
#pragma unroll
    for (int tn = 0; tn < 4; ++tn) {
      const int row0 = rowBase + wr * 64 + tm * 16 + quad * 4;
      const int col  = colBase + wc * 64 + tn * 16 + c16;
#pragma unroll
      for (int r = 0; r < 4; ++r)
        out[(size_t)(row0 + r) * ODIM + col] = acc[tm][tn][r];
    }
}

extern "C" void kernel_launch(void* const* d_in, const int* in_sizes, int n_in,
                              void* d_out, int out_size, void* d_ws, size_t ws_size,
                              hipStream_t stream) {
  const float* x      = (const float*)d_in[0];   // [8192,1024] fp32
  const float* coeffs = (const float*)d_in[1];   // [1024,1024,9] fp32
  float* out = (float*)d_out;                    // [8192,1024] fp32

  char* ws = (char*)d_ws;
  float* stats = (float*)ws;                                           // 64 KB
  __hip_bfloat16* B2T = (__hip_bfloat16*)(ws + 65536);                 // 18.87 MB
  __hip_bfloat16* A2  = (__hip_bfloat16*)(ws + 65536 +
                                          (size_t)ODIM * KDIM * sizeof(__hip_bfloat16));
  // total ws use: 64K + 18.9MB + 151MB ~= 162 MiB

  rowstats_kernel<<<BROWS / 4, 256, 0, stream>>>(x, stats);
  build_a_kernel<<<(BROWS * IDIM) / 256, 256, 0, stream>>>(x, stats, A2);
  build_b_kernel<<<(ODIM * IDIM) / 256, 256, 0, stream>>>(coeffs, B2T);
  gemm_kernel<<<dim3(ODIM / 128, BROWS / 128), 256, 0, stream>>>(
      (const ushort*)A2, (const ushort*)B2T, out);
}

// Round 2
// 364.785 us; speedup vs baseline: 1.0304x; 1.0304x over previous
//
#include <hip/hip_runtime.h>
#include <hip/hip_bf16.h>

// ChebyshevKANLayer: y[b,o] = sum_{i,j} T_j(xhat[b,i]) * C[i,o,j]
//   == GEMM  M=8192 (batch), N=1024 (out), K=1024*9=9216, bf16 inputs, fp32 acc.
// ws layout: [0,64K) row stats | [64K, +18.9MB) B^T bf16 [O][K] | [+, +151MB) A bf16 [M][K]

typedef __attribute__((ext_vector_type(8))) short bf16x8s;   // 8 bf16 = 4 VGPRs (MFMA A/B frag)
typedef __attribute__((ext_vector_type(4))) float f32x4;     // MFMA C/D frag

constexpr int BROWS = 8192;
constexpr int IDIM  = 1024;
constexpr int ODIM  = 1024;
constexpr int DEG1  = 9;
constexpr int KDIM  = IDIM * DEG1;   // 9216

// async global->LDS, 16 B per lane. LDS dst MUST be wave-uniform base + lane*16.
__device__ __forceinline__ void gload_lds16(const void* g, void* l) {
  __builtin_amdgcn_global_load_lds(
      (const __attribute__((address_space(1))) unsigned int*)g,
      (__attribute__((address_space(3))) unsigned int*)l, 16, 0, 0);
}

// ---------- 1. per-row min/max -> (scale, offset):  xhat = scale*x + offset ----------
__global__ __launch_bounds__(256) void rowstats_kernel(const float* __restrict__ x,
                                                       float* __restrict__ stats) {
  const int row  = blockIdx.x * 4 + (threadIdx.x >> 6);   // one wave per row
  const int lane = threadIdx.x & 63;
  const float4* xr = (const float4*)(x + (size_t)row * IDIM);
  float mn = 3.402823466e38f, mx = -3.402823466e38f;
#pragma unroll
  for (int c = 0; c < 4; ++c) {                            // 4*64 float4 = 1024 floats
    float4 v = xr[lane + c * 64];
    mn = fminf(mn, fminf(fminf(v.x, v.y), fminf(v.z, v.w)));
    mx = fmaxf(mx, fmaxf(fmaxf(v.x, v.y), fmaxf(v.z, v.w)));
  }
#pragma unroll
  for (int off = 32; off >= 1; off >>= 1) {
    mn = fminf(mn, __shfl_xor(mn, off));
    mx = fmaxf(mx, __shfl_xor(mx, off));
  }
  if (lane == 0) {
    float inv = 2.0f / (mx - mn);
    stats[row * 2 + 0] = inv;                 // scale
    stats[row * 2 + 1] = -mn * inv - 1.0f;    // offset
  }
}

// ---------- 2. A[b][i*9+j] = T_j(xhat[b,i]) bf16; LDS repack -> uint4 coalesced writes ----
__global__ __launch_bounds__(256) void build_a_kernel(const float* __restrict__ x,
                                                      const float* __restrict__ stats,
                                                      __hip_bfloat16* __restrict__ A2) {
  __shared__ __align__(16) ushort Arow[KDIM];              // 18 KB: one full A row
  const int b = blockIdx.x;
  const int t = threadIdx.x;
  const float sc = stats[b * 2 + 0];
  const float of = stats[b * 2 + 1];
#pragma unroll
  for (int c = 0; c < 4; ++c) {
    const int i = c * 256 + t;
    const float xn = fmaf(sc, x[(size_t)b * IDIM + i], of);
    float T0 = 1.0f, T1 = xn;
    ushort* dst = Arow + i * DEG1;
    dst[0] = ((__hip_bfloat16_raw)__float2bfloat16(1.0f)).x;
    dst[1] = ((__hip_bfloat16_raw)__float2bfloat16(xn)).x;
#pragma unroll
    for (int n = 2; n < DEG1; ++n) {
      float Tn = 2.0f * xn * T1 - T0;
      dst[n] = ((__hip_bfloat16_raw)__float2bfloat16(Tn)).x;
      T0 = T1; T1 = Tn;
    }
  }
  __syncthreads();
  // 9216 ushorts = 1152 uint4, coalesced
  uint4* gdst = (uint4*)(A2 + (size_t)b * KDIM);
  const uint4* lsrc = (const uint4*)Arow;
  for (int idx = t; idx < KDIM / 8; idx += 256) gdst[idx] = lsrc[idx];
}

// ---------- 3. B^T[o][i*9+j] = C[i][o][j] bf16; LDS transpose tile ----------
// tile: i0(32) x o0(64). Coalesced float reads of coeffs, coalesced uint4 writes of B^T.
__global__ __launch_bounds__(256) void build_b_kernel(const float* __restrict__ coeffs,
                                                      __hip_bfloat16* __restrict__ B2T) {
  __shared__ __align__(16) ushort tile[64 * 288];          // 36 KB  [o_l][i_l*9+j]
  const int i0 = blockIdx.x * 32;
  const int o0 = blockIdx.y * 64;
  const int t  = threadIdx.x;
  // read 32*64*9 = 18432 floats; lanes consecutive -> coalesced
  for (int idx = t; idx < 18432; idx += 256) {
    const int i_l = idx / 576;                 // 576 = 64*9 floats per i-row slice
    const int rem = idx - i_l * 576;           // = o_l*9 + j
    const int o_l = rem / 9;
    const int j   = rem - o_l * 9;
    const float v = coeffs[((size_t)(i0 + i_l) * ODIM + o0) * DEG1 + rem];
    tile[o_l * 288 + i_l * DEG1 + j] = ((__hip_bfloat16_raw)__float2bfloat16(v)).x;
  }
  __syncthreads();
  // write 64 rows x 288 ushorts = 2304 uint4, coalesced; dst 16B-aligned (i0*18 % 16 == 0)
  for (int idx = t; idx < 2304; idx += 256) {
    const int o_l = idx / 36;                  // 36 uint4 per o-row
    const int w   = idx - o_l * 36;
    uint4* gdst = (uint4*)((ushort*)B2T + (size_t)(o0 + o_l) * KDIM + i0 * DEG1);
    gdst[w] = ((const uint4*)tile)[idx];
  }
}

// ---------- 4. GEMM: 128x128 tile, BK=32, global_load_lds(16B) staging (m97 structure) ----
__global__ __launch_bounds__(256) void gemm_kernel(const ushort* __restrict__ A2,
                                                   const ushort* __restrict__ B2T,
                                                   float* __restrict__ out) {
  constexpr int BK = 32;
  __shared__ __align__(16) ushort As[128 * BK];   // 8 KB, UNPADDED (global_load_lds layout)
  __shared__ __align__(16) ushort Bs[128 * BK];   // 8 KB

  const int t    = threadIdx.x;
  const int wave = t >> 6;
  const int lane = t & 63;
  const int wr   = wave >> 1;          // wave row 0..1 (64 rows each)
  const int wc   = wave & 1;           // wave col 0..1 (64 cols each)
  const int c16  = lane & 15;
  const int quad = lane >> 4;
  const int rowBase = blockIdx.y * 128;
  const int colBase = blockIdx.x * 128;

  // staging: thread t loads 16B at (row = t>>2, kc = (t&3)*8) and row+64.
  // LDS ushort offset = row*32 + kc = t*8  ->  wave*1024B + lane*16B  (lane-contiguous OK)
  const int srow = t >> 2;
  const int skc  = (t & 3) * 8;
  const ushort* aptr0 = A2  + (size_t)(rowBase + srow) * KDIM + skc;
  const ushort* aptr1 = aptr0 + (size_t)64 * KDIM;
  const ushort* bptr0 = B2T + (size_t)(colBase + srow) * KDIM + skc;
  const ushort* bptr1 = bptr0 + (size_t)64 * KDIM;
  ushort* lA0 = &As[t * 8];
  ushort* lA1 = &As[2048 + t * 8];
  ushort* lB0 = &Bs[t * 8];
  ushort* lB1 = &Bs[2048 + t * 8];

  f32x4 acc[4][4];
#pragma unroll
  for (int a = 0; a < 4; ++a)
#pragma unroll
    for (int b = 0; b < 4; ++b) acc[a][b] = (f32x4){0.f, 0.f, 0.f, 0.f};

  for (int k0 = 0; k0 < KDIM; k0 += BK) {
    __syncthreads();                       // previous tile fully consumed
    gload_lds16(aptr0 + k0, lA0);
    gload_lds16(aptr1 + k0, lA1);
    gload_lds16(bptr0 + k0, lB0);
    gload_lds16(bptr1 + k0, lB1);
    __syncthreads();                       // drains vmcnt -> tile visible

    bf16x8s afr[4], bfr[4];
#pragma unroll
    for (int tm = 0; tm < 4; ++tm)         // A frag: m = lane&15, k = quad*8+j
      afr[tm] = *(const bf16x8s*)&As[(wr * 64 + tm * 16 + c16) * BK + quad * 8];
#pragma unroll
    for (int tn = 0; tn < 4; ++tn)         // B frag: n = lane&15, k = quad*8+j
      bfr[tn] = *(const bf16x8s*)&Bs[(wc * 64 + tn * 16 + c16) * BK + quad * 8];
#pragma unroll
    for (int tm = 0; tm < 4; ++tm)
#pragma unroll
      for (int tn = 0; tn < 4; ++tn)
        acc[tm][tn] = __builtin_amdgcn_mfma_f32_16x16x32_bf16(afr[tm], bfr[tn],
                                                              acc[tm][tn], 0, 0, 0);
  }

  // epilogue: C/D mapping col = lane&15, row = quad*4 + r  (verified m89/m91)
#pragma unroll
  for (int tm = 0; tm < 4; ++tm)
#pragma unroll
    for (int tn = 0; tn < 4; ++tn) {
      const int row0 = rowBase + wr * 64 + tm * 16 + quad * 4;
      const int col  = colBase + wc * 64 + tn * 16 + c16;
#pragma unroll
      for (int r = 0; r < 4; ++r)
        out[(size_t)(row0 + r) * ODIM + col] = acc[tm][tn][r];
    }
}

extern "C" void kernel_launch(void* const* d_in, const int* in_sizes, int n_in,
                              void* d_out, int out_size, void* d_ws, size_t ws_size,
                              hipStream_t stream) {
  const float* x      = (const float*)d_in[0];   // [8192,1024] fp32
  const float* coeffs = (const float*)d_in[1];   // [1024,1024,9] fp32
  float* out = (float*)d_out;                    // [8192,1024] fp32

  char* ws = (char*)d_ws;
  float* stats = (float*)ws;                                           // 64 KB
  __hip_bfloat16* B2T = (__hip_bfloat16*)(ws + 65536);                 // 18.87 MB
  __hip_bfloat16* A2  = (__hip_bfloat16*)(ws + 65536 +
                                          (size_t)ODIM * KDIM * sizeof(__hip_bfloat16));
  // total ws use: 64K + 18.9MB + 151MB ~= 162 MiB

  rowstats_kernel<<<BROWS / 4, 256, 0, stream>>>(x, stats);
  build_a_kernel<<<BROWS, 256, 0, stream>>>(x, stats, A2);
  build_b_kernel<<<dim3(IDIM / 32, ODIM / 64), 256, 0, stream>>>(coeffs, B2T);
  gemm_kernel<<<dim3(ODIM / 128, BROWS / 128), 256, 0, stream>>>(
      (const ushort*)A2, (const ushort*)B2T, out);
}